// Round 3
// baseline (300.324 us; speedup 1.0000x reference)
//
#include <hip/hip_runtime.h>
#include <math.h>

// Problem constants (from reference)
#define NCH   8
#define DNX   128
#define DNY   128
#define KPTS  16384

// Tiling
#define TK    64     // k-values per block
#define XC    16     // x-chunk staged in LDS
#define TKT   4      // tk per thread
#define YT    8      // y per thread
// threads = (TK/TKT) * (DNY/YT) = 16 tk-groups * 16 y-groups = 256

__global__ __launch_bounds__(256, 4)
void nudft_fused_kernel(const float* __restrict__ img_real,
                        const float* __restrict__ img_imag,
                        const float* __restrict__ trj,
                        float* __restrict__ out)
{
    __shared__ float  trjx_s[TK];
    __shared__ float  trjy_s[TK];
    __shared__ float2 pxT[XC][TK];     // [xx][tk], 16*64*8B = 8 KB
    __shared__ float2 simg[XC][DNY];   // [xx][y],  16*128*8B = 16 KB

    const int t  = threadIdx.x;
    const int k0 = blockIdx.x * TK;
    const int c  = blockIdx.y;

    if (t < TK) {
        // trj is (K,2) fp32, interleaved (kx, ky)
        trjx_s[t] = trj[(k0 + t) * 2 + 0];
        trjy_s[t] = trj[(k0 + t) * 2 + 1];
    }

    const int tkg = t >> 4;   // 0..15 : tk group (4 tk each)
    const int yg  = t & 15;   // 0..15 : y group (y = yg + 16*j)

    float accre[TKT][YT];
    float accim[TKT][YT];
    #pragma unroll
    for (int i = 0; i < TKT; ++i)
        #pragma unroll
        for (int j = 0; j < YT; ++j) { accre[i][j] = 0.f; accim[i][j] = 0.f; }

    __syncthreads();   // trj staged

    for (int x0 = 0; x0 < DNX; x0 += XC) {
        __syncthreads();   // previous chunk fully consumed

        // stage px for this x-chunk: phase_x[k,x] = exp(-i*2pi/NX * trjx * (x-64))
        // pi-units: angle/pi = -trjx*(x-64)/64  -> sincospif
        #pragma unroll
        for (int q = 0; q < (XC * TK) / 256; ++q) {    // 4 iters
            int e  = t + 256 * q;
            int xx = e >> 6;        // /TK
            int tk = e & (TK - 1);
            float a = -trjx_s[tk] * (float)(x0 + xx - DNX / 2) * (1.0f / 64.0f);
            float s, cc;
            sincospif(a, &s, &cc);
            pxT[xx][tk] = make_float2(cc, s);
        }

        // stage img chunk (coalesced)
        #pragma unroll
        for (int q = 0; q < (XC * DNY) / 256; ++q) {   // 8 iters
            int e  = t + 256 * q;
            int xx = e >> 7;
            int y  = e & (DNY - 1);
            int g  = (c * DNX + (x0 + xx)) * DNY + y;
            simg[xx][y] = make_float2(img_real[g], img_imag[g]);
        }
        __syncthreads();

        // register-blocked complex MACs: acc[tk][y] += px[tk][x] * img[x][y]
        #pragma unroll 2
        for (int xx = 0; xx < XC; ++xx) {
            float2 m[YT];
            #pragma unroll
            for (int j = 0; j < YT; ++j) m[j] = simg[xx][yg + 16 * j];
            #pragma unroll
            for (int i = 0; i < TKT; ++i) {
                float2 p = pxT[xx][tkg * TKT + i];
                #pragma unroll
                for (int j = 0; j < YT; ++j) {
                    accre[i][j] = fmaf(p.x, m[j].x, accre[i][j]);
                    accre[i][j] = fmaf(-p.y, m[j].y, accre[i][j]);
                    accim[i][j] = fmaf(p.x, m[j].y, accim[i][j]);
                    accim[i][j] = fmaf(p.y, m[j].x, accim[i][j]);
                }
            }
        }
    }

    // stage 2: ksp[c,k] = sum_y acc[k,y] * phase_y[k,y], then 16-lane reduce
    #pragma unroll
    for (int i = 0; i < TKT; ++i) {
        const int tk = tkg * TKT + i;
        const float ty = trjy_s[tk];
        float pr = 0.f, pi = 0.f;
        #pragma unroll
        for (int j = 0; j < YT; ++j) {
            int y = yg + 16 * j;
            float a = -ty * (float)(y - DNY / 2) * (1.0f / 64.0f);
            float s, cc;
            sincospif(a, &s, &cc);
            // (accre + i*accim) * (cc + i*s)
            pr += accre[i][j] * cc - accim[i][j] * s;
            pi += accre[i][j] * s + accim[i][j] * cc;
        }
        // reduce across the 16 lanes (yg = 0..15) of this tk-group
        pr += __shfl_down(pr, 8);  pi += __shfl_down(pi, 8);
        pr += __shfl_down(pr, 4);  pi += __shfl_down(pi, 4);
        pr += __shfl_down(pr, 2);  pi += __shfl_down(pi, 2);
        pr += __shfl_down(pr, 1);  pi += __shfl_down(pi, 1);
        if (yg == 0) {
            const int k = k0 + tk;
            // PLANAR complex output: first NC*K floats = real, next NC*K = imag
            out[(size_t)c * KPTS + k]                       = pr;
            out[(size_t)NCH * KPTS + (size_t)c * KPTS + k]  = pi;
        }
    }
}

extern "C" void kernel_launch(void* const* d_in, const int* in_sizes, int n_in,
                              void* d_out, int out_size, void* d_ws, size_t ws_size,
                              hipStream_t stream)
{
    const float* img_real = (const float*)d_in[0];  // (8,128,128) fp32
    const float* img_imag = (const float*)d_in[1];  // (8,128,128) fp32
    const float* trj      = (const float*)d_in[2];  // (16384,2) fp32
    float* out = (float*)d_out;  // (8,16384) complex64 -> planar: re block then im block

    dim3 grid(KPTS / TK, NCH);
    nudft_fused_kernel<<<grid, 256, 0, stream>>>(img_real, img_imag, trj, out);
}

// Round 4
// 144.897 us; speedup vs baseline: 2.0727x; 2.0727x over previous
//
#include <hip/hip_runtime.h>
#include <math.h>
#include <stdint.h>

// Problem constants
#define NCH   8
#define DNX   128
#define DNY   128
#define KPTS  16384
#define KT    64      // k-points per block; 4 waves, each owns 16 k-rows

typedef __attribute__((ext_vector_type(8))) short bf16x8;   // MFMA A/B frag (8 bf16)
typedef __attribute__((ext_vector_type(4))) float f32x4;    // MFMA C/D frag

// fp32 -> bf16 bits, round-to-nearest-even
__device__ __forceinline__ unsigned short f2bf(float f) {
    union { float f; uint32_t u; } v; v.f = f;
    uint32_t r = (v.u + 0x7fffu + ((v.u >> 16) & 1u)) >> 16;
    return (unsigned short)r;
}

// ---------------------------------------------------------------------------
// Prep: img (fp32 planar re/im) -> B_pre (bf16, per-channel 64KB LDS image).
// Logical B[x][col] with col = 2y+s (s=0:re, 1:im). Stored fragment-order:
// byte addr within channel = (256*col + 64*t4 + 16*q) ^ (16*(col&7)), + 2*j
// where x = 32*t4 + 8*q + j. XOR swizzle -> 2-way-max bank conflicts on frag
// reads (free per m136). One thread per 16B dest chunk; loads coalesced in y.
// ---------------------------------------------------------------------------
__global__ __launch_bounds__(256) void prep_kernel(
    const float* __restrict__ img_real,
    const float* __restrict__ img_imag,
    unsigned short* __restrict__ B_pre)
{
    int tid = blockIdx.x * 256 + threadIdx.x;   // 32768 threads total
    int y  = tid & 127;
    int xc = (tid >> 7) & 15;                   // which 8-x chunk
    int s  = (tid >> 11) & 1;
    int c  = tid >> 12;
    int t4 = xc >> 2, q = xc & 3;
    int x0 = 32 * t4 + 8 * q;
    const float* src = (s ? img_imag : img_real) + c * (DNX * DNY) + y;
    unsigned short pk[8];
    #pragma unroll
    for (int j = 0; j < 8; ++j) pk[j] = f2bf(src[(x0 + j) * DNY]);
    int col  = 2 * y + s;
    int dest = (256 * col + 64 * t4 + 16 * q) ^ (16 * (col & 7));
    uint4 val;
    val.x = (uint32_t)pk[0] | ((uint32_t)pk[1] << 16);
    val.y = (uint32_t)pk[2] | ((uint32_t)pk[3] << 16);
    val.z = (uint32_t)pk[4] | ((uint32_t)pk[5] << 16);
    val.w = (uint32_t)pk[6] | ((uint32_t)pk[7] << 16);
    *(uint4*)((char*)B_pre + (size_t)c * 65536 + dest) = val;
}

// ---------------------------------------------------------------------------
// Main: per block 64 k-points, loop 8 channels.
// Stage 1: acc1[k,col] = sum_x pxr*B, acc2[k,col] = sum_x pxi*B  (MFMA)
// Stage 2: even lane val=A1re=acc1-shfl(acc2), odd val=A1im=acc1+shfl(acc2);
//          kre += val*za, kim += val*zb with per-lane presigned py weights.
// ---------------------------------------------------------------------------
__global__ __launch_bounds__(256) void nudft_mfma_kernel(
    const float* __restrict__ trj,
    const unsigned short* __restrict__ B_pre,
    float* __restrict__ out)
{
    __shared__ __align__(16) unsigned short Bl[2][32768];   // 2 x 64 KB

    const int t    = threadIdx.x;
    const int w    = t >> 6;          // wave id 0..3
    const int lane = t & 63;
    const int m    = lane & 15;       // MFMA m / n / col index
    const int quad = lane >> 4;
    const int spar = lane & 1;        // col parity: 0 = re-col, 1 = im-col
    const int k0   = blockIdx.x * KT;

    // ---- A fragments (px) in registers: A[m=lane&15][x = 32*t4 + 8*quad + j]
    const float trjx = trj[2 * (k0 + w * 16 + m) + 0];
    bf16x8 pxr[4], pxi[4];
    #pragma unroll
    for (int t4 = 0; t4 < 4; ++t4) {
        #pragma unroll
        for (int j = 0; j < 8; ++j) {
            int x = 32 * t4 + 8 * quad + j;
            float a = -trjx * (float)(x - 64) * (1.0f / 64.0f);  // pi-units
            float sa, ca; sincospif(a, &sa, &ca);
            pxr[t4][j] = (short)f2bf(ca);
            pxi[t4][j] = (short)f2bf(sa);
        }
    }

    // ---- stage-2 weights: lane handles k = k0+w*16+quad*4+r, y = ybase+8*ct
    // even lane: (za,zb) = ( pyr, pyi); odd lane: (za,zb) = (-pyi, pyr)
    float ty[4];
    #pragma unroll
    for (int r = 0; r < 4; ++r) ty[r] = trj[2 * (k0 + w * 16 + quad * 4 + r) + 1];
    const int ybase = (lane & 15) >> 1;
    uint32_t zab[16][4];
    #pragma unroll
    for (int ct = 0; ct < 16; ++ct) {
        int y = ybase + 8 * ct;
        #pragma unroll
        for (int r = 0; r < 4; ++r) {
            float b = -ty[r] * (float)(y - 64) * (1.0f / 64.0f);
            float sb, cb; sincospif(b, &sb, &cb);
            float za = spar ? -sb : cb;
            float zb = spar ?  cb : sb;
            zab[ct][r] = (uint32_t)f2bf(za) | ((uint32_t)f2bf(zb) << 16);
        }
    }
    const float sgn = spar ? 1.0f : -1.0f;   // val = acc1 + sgn*shfl(acc2)

    // ---- stage channel 0 into buffer 0 (identity copy of prep image)
    #pragma unroll
    for (int i = 0; i < 16; ++i) {
        size_t off = ((size_t)i * 256 + t) * 16;
        *(uint4*)((char*)&Bl[0][0] + off) = *(const uint4*)((const char*)B_pre + off);
    }
    __syncthreads();

    for (int c = 0; c < NCH; ++c) {
        const int buf = c & 1;

        // prefetch next channel into registers (hides L2 latency under MFMA)
        uint4 pf[16];
        if (c + 1 < NCH) {
            #pragma unroll
            for (int i = 0; i < 16; ++i) {
                size_t off = ((size_t)i * 256 + t) * 16;
                pf[i] = *(const uint4*)((const char*)B_pre + (size_t)(c + 1) * 65536 + off);
            }
        }

        float kre[4] = {0.f, 0.f, 0.f, 0.f};
        float kim[4] = {0.f, 0.f, 0.f, 0.f};

        #pragma unroll
        for (int ct = 0; ct < 16; ++ct) {
            f32x4 acc1 = {0.f, 0.f, 0.f, 0.f};
            f32x4 acc2 = {0.f, 0.f, 0.f, 0.f};
            const int col = ct * 16 + m;
            #pragma unroll
            for (int t4 = 0; t4 < 4; ++t4) {
                int addr = (256 * col + 64 * t4 + 16 * quad) ^ (16 * (col & 7));
                bf16x8 bfrag = *(const bf16x8*)((const char*)&Bl[buf][0] + addr);
                acc1 = __builtin_amdgcn_mfma_f32_16x16x32_bf16(pxr[t4], bfrag, acc1, 0, 0, 0);
                acc2 = __builtin_amdgcn_mfma_f32_16x16x32_bf16(pxi[t4], bfrag, acc2, 0, 0, 0);
            }
            #pragma unroll
            for (int r = 0; r < 4; ++r) {
                float tsh = __shfl_xor(acc2[r], 1, 64);
                float val = fmaf(sgn, tsh, acc1[r]);      // even: A1re, odd: A1im
                uint32_t u = zab[ct][r];
                float za = __uint_as_float(u << 16);
                float zb = __uint_as_float(u & 0xffff0000u);
                kre[r] = fmaf(val, za, kre[r]);
                kim[r] = fmaf(val, zb, kim[r]);
            }
        }

        // write prefetched channel into the other buffer
        if (c + 1 < NCH) {
            #pragma unroll
            for (int i = 0; i < 16; ++i) {
                size_t off = ((size_t)i * 256 + t) * 16;
                *(uint4*)((char*)&Bl[buf ^ 1][0] + off) = pf[i];
            }
        }

        // 16-lane butterfly reduce (sums all parities & ybase -> full y-sum)
        #pragma unroll
        for (int r = 0; r < 4; ++r) {
            #pragma unroll
            for (int o = 1; o <= 8; o <<= 1) {
                kre[r] += __shfl_xor(kre[r], o, 64);
                kim[r] += __shfl_xor(kim[r], o, 64);
            }
        }
        if (m == 0) {
            #pragma unroll
            for (int r = 0; r < 4; ++r) {
                int k = k0 + w * 16 + quad * 4 + r;
                out[(size_t)c * KPTS + k]                        = kre[r];
                out[(size_t)NCH * KPTS + (size_t)c * KPTS + k]   = kim[r];
            }
        }
        __syncthreads();   // protects Bl[buf^1] writes vs next-iter reads
    }
}

extern "C" void kernel_launch(void* const* d_in, const int* in_sizes, int n_in,
                              void* d_out, int out_size, void* d_ws, size_t ws_size,
                              hipStream_t stream)
{
    const float* img_real = (const float*)d_in[0];  // (8,128,128) fp32
    const float* img_imag = (const float*)d_in[1];  // (8,128,128) fp32
    const float* trj      = (const float*)d_in[2];  // (16384,2) fp32
    float* out = (float*)d_out;                      // planar: re block then im block
    unsigned short* B_pre = (unsigned short*)d_ws;   // 512 KB bf16 pre-swizzled img

    prep_kernel<<<128, 256, 0, stream>>>(img_real, img_imag, B_pre);
    nudft_mfma_kernel<<<KPTS / KT, 256, 0, stream>>>(trj, B_pre, out);
}

// Round 5
// 88.680 us; speedup vs baseline: 3.3866x; 1.6339x over previous
//
#include <hip/hip_runtime.h>
#include <math.h>
#include <stdint.h>

// Problem constants
#define NCH   8
#define DNX   128
#define DNY   128
#define KPTS  16384

typedef __attribute__((ext_vector_type(8))) short bf16x8;   // MFMA A/B frag (8 bf16)
typedef __attribute__((ext_vector_type(4))) float f32x4;    // MFMA C/D frag

typedef const __attribute__((address_space(1))) unsigned int* gp_t;
typedef __attribute__((address_space(3))) unsigned int* lp_t;

// fp32 -> bf16 bits, round-to-nearest-even
__device__ __forceinline__ unsigned short f2bf(float f) {
    union { float f; uint32_t u; } v; v.f = f;
    uint32_t r = (v.u + 0x7fffu + ((v.u >> 16) & 1u)) >> 16;
    return (unsigned short)r;
}

// ---------------------------------------------------------------------------
// Prep: img (fp32 planar re/im) -> B_pre (bf16, per-channel 64KB image in the
// exact LDS layout). Logical B[x][col], col = 2y+s (s=0:re, 1:im). Address:
// (256*col + 64*t4 + 16*q) ^ (16*(col&7)), x = 32*t4 + 8*q + j, +2*j.
// (verified correct in round 4)
// ---------------------------------------------------------------------------
__global__ __launch_bounds__(256) void prep_kernel(
    const float* __restrict__ img_real,
    const float* __restrict__ img_imag,
    unsigned short* __restrict__ B_pre)
{
    int tid = blockIdx.x * 256 + threadIdx.x;   // 32768 threads total
    int y  = tid & 127;
    int xc = (tid >> 7) & 15;                   // which 8-x chunk
    int s  = (tid >> 11) & 1;
    int c  = tid >> 12;
    int t4 = xc >> 2, q = xc & 3;
    int x0 = 32 * t4 + 8 * q;
    const float* src = (s ? img_imag : img_real) + c * (DNX * DNY) + y;
    unsigned short pk[8];
    #pragma unroll
    for (int j = 0; j < 8; ++j) pk[j] = f2bf(src[(x0 + j) * DNY]);
    int col  = 2 * y + s;
    int dest = (256 * col + 64 * t4 + 16 * q) ^ (16 * (col & 7));
    uint4 val;
    val.x = (uint32_t)pk[0] | ((uint32_t)pk[1] << 16);
    val.y = (uint32_t)pk[2] | ((uint32_t)pk[3] << 16);
    val.z = (uint32_t)pk[4] | ((uint32_t)pk[5] << 16);
    val.w = (uint32_t)pk[6] | ((uint32_t)pk[7] << 16);
    *(uint4*)((char*)B_pre + (size_t)c * 65536 + dest) = val;
}

// ---------------------------------------------------------------------------
// Main: block = 4 waves, each wave owns 32 k (2 k-groups of 16).
// Block covers 128 k x 2 channels. Grid (128 kblocks, 4 chan-groups).
// Stage 1 (MFMA 16x16x32): acc1[kg] += pxr[kg]*B, acc2[kg] += pxi[kg]*B
//   -> each B fragment read feeds 4 MFMAs (2 kg x {cos,sin}).
// Stage 2 (per-lane): val = A1re/A1im via lane^1 shuffle; weights (za,zb)
//   generated by incremental rotation (y step 8 per ct => fixed rotor/k-row;
//   odd parity = even rotated +90 deg, same recurrence).
// ---------------------------------------------------------------------------
__global__ __launch_bounds__(256, 2) void nudft_mfma_kernel(
    const float* __restrict__ trj,
    const unsigned short* __restrict__ B_pre,
    float* __restrict__ out)
{
    __shared__ __align__(16) unsigned short Bl[32768];   // 64 KB single buffer

    const int t    = threadIdx.x;
    const int w    = t >> 6;          // wave 0..3
    const int lane = t & 63;
    const int m    = lane & 15;       // MFMA row (A) / col (C) index
    const int quad = (lane >> 4) & 3;
    const int spar = m & 1;           // col parity: 0 = re-col, 1 = im-col
    const int kb   = blockIdx.x;      // 0..127
    const int cg   = blockIdx.y;      // 0..3 -> channels 2cg, 2cg+1
    const int k0w  = kb * 128 + w * 32;

    // ---- A fragments (px) in registers: A[m][x = 32*t4 + 8*quad + j]
    bf16x8 pxr[2][4], pxi[2][4];
    #pragma unroll
    for (int kg = 0; kg < 2; ++kg) {
        const float trjx = trj[2 * (k0w + kg * 16 + m) + 0];
        #pragma unroll
        for (int t4 = 0; t4 < 4; ++t4) {
            #pragma unroll
            for (int j = 0; j < 8; ++j) {
                int x = 32 * t4 + 8 * quad + j;
                float a = -trjx * (float)(x - 64) * (1.0f / 64.0f);  // pi-units
                float sa, ca; sincospif(a, &sa, &ca);
                pxr[kg][t4][j] = (short)f2bf(ca);
                pxi[kg][t4][j] = (short)f2bf(sa);
            }
        }
    }

    // ---- stage-2 rotation state. Lane element (kg,r): row k = k0w+kg*16+quad*4+r,
    // y = ct*8 + ybase, ybase = m>>1. Weight angle b = -ty*(y-64)/64 (pi-units);
    // step per ct: delta = -ty/8. even lane (za,zb)=(cb,sb); odd = (-sb,cb).
    const int ybase = m >> 1;
    float za0[8], zb0[8], drs[8], dis[8];
    #pragma unroll
    for (int kg = 0; kg < 2; ++kg) {
        #pragma unroll
        for (int r = 0; r < 4; ++r) {
            int idx = kg * 4 + r;
            float ty = trj[2 * (k0w + kg * 16 + quad * 4 + r) + 1];
            float b0 = -ty * (float)(ybase - 64) * (1.0f / 64.0f);
            float sb, cb; sincospif(b0, &sb, &cb);
            za0[idx] = spar ? -sb : cb;
            zb0[idx] = spar ?  cb : sb;
            float sd, cd; sincospif(-ty * 0.125f, &sd, &cd);
            drs[idx] = cd; dis[idx] = sd;
        }
    }
    const float sgn = spar ? 1.0f : -1.0f;   // val = acc1 + sgn*shfl(acc2)

    const int A0 = 256 * m + 16 * quad;
    const int Mx = 16 * (m & 7);             // XOR swizzle mask (col&7 == m&7)

    #pragma unroll 1
    for (int cc = 0; cc < 2; ++cc) {
        const int c = cg * 2 + cc;

        __syncthreads();   // previous channel fully consumed
        // stage channel c: wave w copies its 16 KB slice via async DMA
        {
            const char* gbase = (const char*)B_pre + ((size_t)c << 16) + (w << 14) + (lane << 4);
            char* lbase = (char*)&Bl[0] + (w << 14);
            #pragma unroll
            for (int i = 0; i < 16; ++i) {
                __builtin_amdgcn_global_load_lds(
                    (gp_t)(const void*)(gbase + (i << 10)),
                    (lp_t)(void*)(lbase + (i << 10)),
                    16, 0, 0);
            }
        }
        __syncthreads();   // DMA drained (vmcnt(0) before barrier)

        float za[8], zb[8], kre[8], kim[8];
        #pragma unroll
        for (int idx = 0; idx < 8; ++idx) {
            za[idx] = za0[idx]; zb[idx] = zb0[idx];
            kre[idx] = 0.f; kim[idx] = 0.f;
        }

        #pragma unroll 1
        for (int ct = 0; ct < 16; ++ct) {
            f32x4 acc1[2], acc2[2];
            #pragma unroll
            for (int kg = 0; kg < 2; ++kg) {
                acc1[kg] = (f32x4){0.f, 0.f, 0.f, 0.f};
                acc2[kg] = (f32x4){0.f, 0.f, 0.f, 0.f};
            }
            const int Act = A0 + 4096 * ct;
            #pragma unroll
            for (int t4 = 0; t4 < 4; ++t4) {
                int addr = (Act + 64 * t4) ^ Mx;
                bf16x8 bfrag = *(const bf16x8*)((const char*)&Bl[0] + addr);
                acc1[0] = __builtin_amdgcn_mfma_f32_16x16x32_bf16(pxr[0][t4], bfrag, acc1[0], 0, 0, 0);
                acc2[0] = __builtin_amdgcn_mfma_f32_16x16x32_bf16(pxi[0][t4], bfrag, acc2[0], 0, 0, 0);
                acc1[1] = __builtin_amdgcn_mfma_f32_16x16x32_bf16(pxr[1][t4], bfrag, acc1[1], 0, 0, 0);
                acc2[1] = __builtin_amdgcn_mfma_f32_16x16x32_bf16(pxi[1][t4], bfrag, acc2[1], 0, 0, 0);
            }
            #pragma unroll
            for (int kg = 0; kg < 2; ++kg) {
                #pragma unroll
                for (int r = 0; r < 4; ++r) {
                    const int idx = kg * 4 + r;
                    float tsh = __shfl_xor(acc2[kg][r], 1, 64);
                    float val = fmaf(sgn, tsh, acc1[kg][r]);   // even: A1re, odd: A1im
                    kre[idx] = fmaf(val, za[idx], kre[idx]);
                    kim[idx] = fmaf(val, zb[idx], kim[idx]);
                    // advance rotor (old values on RHS only)
                    float tz = za[idx] * drs[idx] - zb[idx] * dis[idx];
                    zb[idx]  = fmaf(za[idx], dis[idx], zb[idx] * drs[idx]);
                    za[idx]  = tz;
                }
            }
        }

        // 16-lane butterfly (sums parities + all ybase -> full y-sum)
        #pragma unroll
        for (int idx = 0; idx < 8; ++idx) {
            #pragma unroll
            for (int o = 1; o <= 8; o <<= 1) {
                kre[idx] += __shfl_xor(kre[idx], o, 64);
                kim[idx] += __shfl_xor(kim[idx], o, 64);
            }
        }
        if (m == 0) {
            #pragma unroll
            for (int kg = 0; kg < 2; ++kg) {
                #pragma unroll
                for (int r = 0; r < 4; ++r) {
                    int k = k0w + kg * 16 + quad * 4 + r;
                    out[(size_t)c * KPTS + k]                       = kre[kg * 4 + r];
                    out[(size_t)NCH * KPTS + (size_t)c * KPTS + k]  = kim[kg * 4 + r];
                }
            }
        }
    }
}

extern "C" void kernel_launch(void* const* d_in, const int* in_sizes, int n_in,
                              void* d_out, int out_size, void* d_ws, size_t ws_size,
                              hipStream_t stream)
{
    const float* img_real = (const float*)d_in[0];  // (8,128,128) fp32
    const float* img_imag = (const float*)d_in[1];  // (8,128,128) fp32
    const float* trj      = (const float*)d_in[2];  // (16384,2) fp32
    float* out = (float*)d_out;                      // planar: re block then im block
    unsigned short* B_pre = (unsigned short*)d_ws;   // 512 KB bf16 pre-swizzled img

    prep_kernel<<<128, 256, 0, stream>>>(img_real, img_imag, B_pre);
    nudft_mfma_kernel<<<dim3(128, 4), 256, 0, stream>>>(trj, B_pre, out);
}

// Round 6
// 80.253 us; speedup vs baseline: 3.7422x; 1.1050x over previous
//
#include <hip/hip_runtime.h>
#include <math.h>
#include <stdint.h>

// Problem constants
#define NCH   8
#define DNX   128
#define DNY   128
#define KPTS  16384

typedef __attribute__((ext_vector_type(8))) short bf16x8;   // MFMA A/B frag (8 bf16)
typedef __attribute__((ext_vector_type(4))) float f32x4;    // MFMA C/D frag

typedef const __attribute__((address_space(1))) unsigned int* gp_t;
typedef __attribute__((address_space(3))) unsigned int* lp_t;

// fp32 -> bf16 bits, round-to-nearest-even
__device__ __forceinline__ unsigned short f2bf(float f) {
    union { float f; uint32_t u; } v; v.f = f;
    uint32_t r = (v.u + 0x7fffu + ((v.u >> 16) & 1u)) >> 16;
    return (unsigned short)r;
}

// Sum over each 16-lane row via DPP (pure VALU — keeps LDS pipe free).
// Steps: xor1 (quad_perm 1,0,3,2), xor2 (quad_perm 2,3,0,1),
// row_half_mirror (cross-quad within 8), row_mirror (cross-half within 16).
__device__ __forceinline__ float dpp_sum16(float v) {
    v += __int_as_float(__builtin_amdgcn_update_dpp(0, __float_as_int(v), 0xB1,  0xF, 0xF, true));
    v += __int_as_float(__builtin_amdgcn_update_dpp(0, __float_as_int(v), 0x4E,  0xF, 0xF, true));
    v += __int_as_float(__builtin_amdgcn_update_dpp(0, __float_as_int(v), 0x141, 0xF, 0xF, true));
    v += __int_as_float(__builtin_amdgcn_update_dpp(0, __float_as_int(v), 0x140, 0xF, 0xF, true));
    return v;
}

// ---------------------------------------------------------------------------
// Prep: img (fp32 planar re/im) -> B_pre (bf16, per-channel 64KB image in the
// exact LDS layout). Logical B[x][col], col = 2y+s (s=0:re, 1:im). Address:
// (256*col + 64*t4 + 16*q) ^ (16*(col&7)), x = 32*t4 + 8*q + j, +2*j.
// (verified correct rounds 4-5)
// ---------------------------------------------------------------------------
__global__ __launch_bounds__(256) void prep_kernel(
    const float* __restrict__ img_real,
    const float* __restrict__ img_imag,
    unsigned short* __restrict__ B_pre)
{
    int tid = blockIdx.x * 256 + threadIdx.x;   // 32768 threads total
    int y  = tid & 127;
    int xc = (tid >> 7) & 15;                   // which 8-x chunk
    int s  = (tid >> 11) & 1;
    int c  = tid >> 12;
    int t4 = xc >> 2, q = xc & 3;
    int x0 = 32 * t4 + 8 * q;
    const float* src = (s ? img_imag : img_real) + c * (DNX * DNY) + y;
    unsigned short pk[8];
    #pragma unroll
    for (int j = 0; j < 8; ++j) pk[j] = f2bf(src[(x0 + j) * DNY]);
    int col  = 2 * y + s;
    int dest = (256 * col + 64 * t4 + 16 * q) ^ (16 * (col & 7));
    uint4 val;
    val.x = (uint32_t)pk[0] | ((uint32_t)pk[1] << 16);
    val.y = (uint32_t)pk[2] | ((uint32_t)pk[3] << 16);
    val.z = (uint32_t)pk[4] | ((uint32_t)pk[5] << 16);
    val.w = (uint32_t)pk[6] | ((uint32_t)pk[7] << 16);
    *(uint4*)((char*)B_pre + (size_t)c * 65536 + dest) = val;
}

// ---------------------------------------------------------------------------
// Main: block = 4 waves, each wave owns 32 k (2 k-groups of 16).
// Grid (128 kblocks, 4 chan-groups of 2 channels).
// Stage 1 (MFMA 16x16x32): acc1 += cos_frag*B, acc2 += sin_frag*B; one B
//   fragment read feeds 4 MFMAs.
// Stage 2 (lane-local, shuffle-free): F = sum acc1*cb - acc2*sb,
//   G = sum acc1*sb + acc2*cb with (cb,sb) advanced by incremental rotation;
//   kre-part = even-col ? F : -G, kim-part = even-col ? G : F;
//   16-lane DPP reduction at the end.
// ---------------------------------------------------------------------------
__global__ __launch_bounds__(256, 2) void nudft_mfma_kernel(
    const float* __restrict__ trj,
    const unsigned short* __restrict__ B_pre,
    float* __restrict__ out)
{
    __shared__ __align__(16) unsigned short Bl[32768];   // 64 KB single buffer

    const int t    = threadIdx.x;
    const int w    = t >> 6;          // wave 0..3
    const int lane = t & 63;
    const int m    = lane & 15;       // MFMA row (A) / col (C) index
    const int quad = (lane >> 4) & 3;
    const int spar = m & 1;           // col parity: 0 = re-col, 1 = im-col
    const int kb   = blockIdx.x;      // 0..127
    const int cg   = blockIdx.y;      // 0..3 -> channels 2cg, 2cg+1
    const int k0w  = kb * 128 + w * 32;

    // ---- A fragments (px) via incremental rotation:
    // A[m][x = 32*t4 + 8*quad + j]; theta(x) = d1*(x-64) pi-units, d1 = -trjx/64
    bf16x8 pxr[2][4], pxi[2][4];
    #pragma unroll
    for (int kg = 0; kg < 2; ++kg) {
        const float trjx = trj[2 * (k0w + kg * 16 + m) + 0];
        const float d1 = -trjx * (1.0f / 64.0f);
        float s1, c1;  sincospif(d1, &s1, &c1);            // rot per +1 x
        float s32, c32; sincospif(d1 * 32.0f, &s32, &c32); // rot per +32 x (t4 step)
        float ps, pc;  sincospif(d1 * (float)(8 * quad - 64), &ps, &pc); // x = 8*quad
        #pragma unroll
        for (int t4 = 0; t4 < 4; ++t4) {
            float qc = pc, qs = ps;
            #pragma unroll
            for (int j = 0; j < 8; ++j) {
                pxr[kg][t4][j] = (short)f2bf(qc);
                pxi[kg][t4][j] = (short)f2bf(qs);
                if (j < 7) {
                    float tq = qc * c1 - qs * s1;
                    qs = fmaf(qc, s1, qs * c1);
                    qc = tq;
                }
            }
            if (t4 < 3) {
                float tp = pc * c32 - ps * s32;
                ps = fmaf(pc, s32, ps * c32);
                pc = tp;
            }
        }
    }

    // ---- stage-2 rotor init. Lane element idx=(kg,r): k = k0w+kg*16+quad*4+r,
    // y = ct*8 + ybase, ybase = m>>1. (cb,sb) = cos/sin(pi * -ty*(y-64)/64);
    // per-ct step rotor (dr,di) = cos/sin(pi * -ty/8). Parity-independent.
    const int ybase = m >> 1;
    float cb0[8], sb0[8], dr[8], di[8];
    #pragma unroll
    for (int kg = 0; kg < 2; ++kg) {
        #pragma unroll
        for (int r = 0; r < 4; ++r) {
            int idx = kg * 4 + r;
            float ty = trj[2 * (k0w + kg * 16 + quad * 4 + r) + 1];
            float sb, cbv; sincospif(-ty * (float)(ybase - 64) * (1.0f / 64.0f), &sb, &cbv);
            cb0[idx] = cbv; sb0[idx] = sb;
            float sd, cd; sincospif(-ty * 0.125f, &sd, &cd);
            dr[idx] = cd; di[idx] = sd;
        }
    }

    const int A0 = 256 * m + 16 * quad;
    const int Mx = 16 * (m & 7);             // XOR swizzle mask (col&7 == m&7)

    #pragma unroll 1
    for (int cc = 0; cc < 2; ++cc) {
        const int c = cg * 2 + cc;

        __syncthreads();   // previous channel fully consumed
        // stage channel c: wave w DMA-copies its 16 KB slice
        {
            const char* gbase = (const char*)B_pre + ((size_t)c << 16) + (w << 14) + (lane << 4);
            char* lbase = (char*)&Bl[0] + (w << 14);
            #pragma unroll
            for (int i = 0; i < 16; ++i) {
                __builtin_amdgcn_global_load_lds(
                    (gp_t)(const void*)(gbase + (i << 10)),
                    (lp_t)(void*)(lbase + (i << 10)),
                    16, 0, 0);
            }
        }
        __syncthreads();   // DMA drained (vmcnt(0) before barrier)

        float F[8], G[8], cb[8], sb[8];
        #pragma unroll
        for (int idx = 0; idx < 8; ++idx) {
            F[idx] = 0.f; G[idx] = 0.f;
            cb[idx] = cb0[idx]; sb[idx] = sb0[idx];
        }

        #pragma unroll 2
        for (int ct = 0; ct < 16; ++ct) {
            f32x4 acc1[2], acc2[2];
            #pragma unroll
            for (int kg = 0; kg < 2; ++kg) {
                acc1[kg] = (f32x4){0.f, 0.f, 0.f, 0.f};
                acc2[kg] = (f32x4){0.f, 0.f, 0.f, 0.f};
            }
            const int Act = A0 + 4096 * ct;
            #pragma unroll
            for (int t4 = 0; t4 < 4; ++t4) {
                int addr = (Act + 64 * t4) ^ Mx;
                bf16x8 bfrag = *(const bf16x8*)((const char*)&Bl[0] + addr);
                acc1[0] = __builtin_amdgcn_mfma_f32_16x16x32_bf16(pxr[0][t4], bfrag, acc1[0], 0, 0, 0);
                acc2[0] = __builtin_amdgcn_mfma_f32_16x16x32_bf16(pxi[0][t4], bfrag, acc2[0], 0, 0, 0);
                acc1[1] = __builtin_amdgcn_mfma_f32_16x16x32_bf16(pxr[1][t4], bfrag, acc1[1], 0, 0, 0);
                acc2[1] = __builtin_amdgcn_mfma_f32_16x16x32_bf16(pxi[1][t4], bfrag, acc2[1], 0, 0, 0);
            }
            #pragma unroll
            for (int kg = 0; kg < 2; ++kg) {
                #pragma unroll
                for (int r = 0; r < 4; ++r) {
                    const int idx = kg * 4 + r;
                    float a1 = acc1[kg][r], a2 = acc2[kg][r];
                    F[idx] = fmaf(a1, cb[idx], F[idx]);
                    F[idx] = fmaf(-a2, sb[idx], F[idx]);
                    G[idx] = fmaf(a1, sb[idx], G[idx]);
                    G[idx] = fmaf(a2, cb[idx], G[idx]);
                    // advance rotor
                    float tz = cb[idx] * dr[idx] - sb[idx] * di[idx];
                    sb[idx]  = fmaf(cb[idx], di[idx], sb[idx] * dr[idx]);
                    cb[idx]  = tz;
                }
            }
        }

        // per-lane parity assignment, then 16-lane DPP reduction (VALU only)
        #pragma unroll
        for (int idx = 0; idx < 8; ++idx) {
            float kre_p = spar ? -G[idx] : F[idx];
            float kim_p = spar ?  F[idx] : G[idx];
            float kre_s = dpp_sum16(kre_p);
            float kim_s = dpp_sum16(kim_p);
            if (m == 0) {
                int kg = idx >> 2, r = idx & 3;
                int k = k0w + kg * 16 + quad * 4 + r;
                out[(size_t)c * KPTS + k]                      = kre_s;
                out[(size_t)NCH * KPTS + (size_t)c * KPTS + k] = kim_s;
            }
        }
    }
}

extern "C" void kernel_launch(void* const* d_in, const int* in_sizes, int n_in,
                              void* d_out, int out_size, void* d_ws, size_t ws_size,
                              hipStream_t stream)
{
    const float* img_real = (const float*)d_in[0];  // (8,128,128) fp32
    const float* img_imag = (const float*)d_in[1];  // (8,128,128) fp32
    const float* trj      = (const float*)d_in[2];  // (16384,2) fp32
    float* out = (float*)d_out;                      // planar: re block then im block
    unsigned short* B_pre = (unsigned short*)d_ws;   // 512 KB bf16 pre-swizzled img

    prep_kernel<<<128, 256, 0, stream>>>(img_real, img_imag, B_pre);
    nudft_mfma_kernel<<<dim3(128, 4), 256, 0, stream>>>(trj, B_pre, out);
}